// Round 10
// baseline (215.666 us; speedup 1.0000x reference)
//
#include <hip/hip_runtime.h>
#include <hip/hip_cooperative_groups.h>
#include <hip/hip_bf16.h>
#include <stdint.h>

namespace cg = cooperative_groups;

#define S_LEN 2048
#define D_DIM 1024
#define P_DIM 256
#define NQ_   8192
#define M_TOT 16384  // B*S
#define CAP 32       // max span-endpoints per H row
#define HS  260      // padded f32 row stride for H tile in LDS

typedef __attribute__((ext_vector_type(4))) float  f32x4;
typedef __attribute__((ext_vector_type(8))) __bf16 bf16x8;

// ============================================================================
// Fragment spec (harness-verified, lane l = q*16+lm):
//   A-frag(mi,kt,kh): lane l elem e = A[m0+mi*16+lm][kt*64+(kh*4+q)*8+e]
//     in LDS at (mi*32+kt*2+kh)*512 + qp*128 + (lm^(qp<<1))*8   (bank swizzle)
//   B-frag(c16,kt,kh) in WTf at (c16*32+kt*2+kh)*512 + l*8:
//     lane l elem e = W[kt*64+(kh*4+q)*8+e][c16*16+lm]
// ============================================================================

// Single cooperative kernel, 256 blocks x 512 thr = 1 block/CU (137 KB LDS
// forces it; grid == #CUs so co-residency holds). Phases:
//  pre-sync1 : LOADQ(q0,q1) A-prefetch (HBM kicked first), cnt zeroing,
//              W 32x32-tile -> WTf frag store (scratch overlays elist LDS),
//              WRITEQ(q0), invalid-span zeroing (no cnt dependency).
//  grid.sync #1: cnt zeroed + WTf visible grid-wide.
//  post-sync1: LOADB(0,0)/(1,1) B-prefetch, bucket atomics.
//  grid.sync #2: buckets complete grid-wide.
//  compute   : verified R9 quarter-pipelined chain (stagger ph4 de-convoys
//              the shared WTf sweep; B reg triple-buffer, literal indices).
//  epilogue  : verified span scatter from LDS H-tile.
__global__ __launch_bounds__(512, 1) void fused_kernel(const float*  __restrict__ A,
                                                       const float*  __restrict__ W,
                                                       const float*  __restrict__ bias,
                                                       const int*    __restrict__ s1,
                                                       const int*    __restrict__ e1,
                                                       const int*    __restrict__ s2,
                                                       const int*    __restrict__ e2,
                                                       const int*    __restrict__ qb,
                                                       int*          __restrict__ cnt,
                                                       int*          __restrict__ bucket,
                                                       __bf16*       __restrict__ WTf,
                                                       float*        __restrict__ out) {
    __shared__ __align__(16) __bf16 Afl[65536];   // 128 KB A-panel fragments
    __shared__ int s_cnt[64];
    __shared__ int s_off[65];
    __shared__ int elist[64 * CAP];               // epilogue list; W scratch pre-sync1

    const int tid = threadIdx.x;
    const int w   = tid >> 6;             // wave 0..7
    const int l   = tid & 63;
    const int lm  = l & 15;
    const int q   = l >> 4;

    const int bx  = blockIdx.x;
    const int m0  = bx * 64;
    const int ph4 = bx & 3;               // quarter stagger

    // ---- A staging geometry ----
    const int r    = tid >> 3;
    const int la   = tid & 7;
    const int mi_s = r >> 4, lmr = r & 15;
    const float* asrc = A + (size_t)(m0 + r) * D_DIM;

    float4 fA[8], fB[8];
#define LOADQ(QQ, FR) {                                                       \
    _Pragma("unroll") for (int it = 0; it < 4; ++it) {                        \
        const int c = (QQ) * 32 + it * 8 + la;                                \
        FR[it * 2]     = *(const float4*)(asrc + c * 8);                      \
        FR[it * 2 + 1] = *(const float4*)(asrc + c * 8 + 4); } }
#define WRITEQ(QQ, FR) {                                                      \
    _Pragma("unroll") for (int it = 0; it < 4; ++it) {                        \
        const int c = (QQ) * 32 + it * 8 + la;                                \
        bf16x8 v;                                                             \
        v[0] = (__bf16)FR[it*2].x;   v[1] = (__bf16)FR[it*2].y;               \
        v[2] = (__bf16)FR[it*2].z;   v[3] = (__bf16)FR[it*2].w;               \
        v[4] = (__bf16)FR[it*2+1].x; v[5] = (__bf16)FR[it*2+1].y;             \
        v[6] = (__bf16)FR[it*2+1].z; v[7] = (__bf16)FR[it*2+1].w;             \
        const int kt = c >> 3, kh = (c >> 2) & 1, qp = c & 3;                 \
        const int slot = lmr ^ (qp << 1);                                     \
        *(bf16x8*)(&Afl[(mi_s * 32 + kt * 2 + kh) * 512 + qp * 128 + slot * 8]) = v; } }

    const int q0 = ph4, q1 = (ph4 + 1) & 3, q2 = (ph4 + 2) & 3, q3 = (ph4 + 3) & 3;

    LOADQ(q0, fA)                         // kick the HBM A-stream first
    LOADQ(q1, fB)

    // ---- cnt zeroing (own 64 entries) ----
    if (tid < 64) cnt[bx * 64 + tid] = 0;

    // ---- W tile -> WTf fragments (scratch = elist area, f32[32][33]) --------
    {
        float* wscr = (float*)elist;
        const int kx = bx & 31, ny = bx >> 5;      // k-tile, n-tile
        const int tx = tid & 31, ty0 = tid >> 5;   // ty0 0..15
        wscr[ty0 * 33 + tx]        = W[(kx * 32 + ty0) * P_DIM + ny * 32 + tx];
        wscr[(ty0 + 16) * 33 + tx] = W[(kx * 32 + ty0 + 16) * P_DIM + ny * 32 + tx];
        __syncthreads();
        if (tid < 128) {                   // 2 c16r * 4 q * 16 lm writers
            const int c16r = tid >> 6, qq = (tid >> 4) & 3, lmm = tid & 15;
            bf16x8 v;
            #pragma unroll
            for (int e = 0; e < 8; ++e) v[e] = (__bf16)wscr[(qq * 8 + e) * 33 + c16r * 16 + lmm];
            const int c16 = ny * 2 + c16r, ts = kx >> 1, kh = kx & 1;
            *(bf16x8*)(WTf + (size_t)((c16 * 32 + ts * 2 + kh) * 512 + (qq * 16 + lmm) * 8)) = v;
        }
    }

    WRITEQ(q0, fA)                        // Afl; waits fA via counted vmcnt

    // ---- invalid-span zeroing (verified ballot form; gw < 512) --------------
    const int gw = bx * 8 + w;
    int sv = 0, ev = -1, bv = 0, seth = 0, halfh = 0, qz = 0, bqw = 0;
    if (gw < 512) {
        seth  = (gw >> 1) & 1;
        halfh = gw & 1;
        bqw   = (gw >> 2) * 64;
        qz    = bqw + l;
        bv    = qb[qz];
        sv    = seth ? s2[qz] : s1[qz];
        ev    = seth ? e2[qz] : e1[qz];
        unsigned long long mask = __ballot(ev < sv);
        const float4 z = make_float4(0.f, 0.f, 0.f, 0.f);
        while (mask) {
            const int j = __ffsll(mask) - 1;
            mask &= mask - 1;
            float* dst = out + (size_t)seth * (NQ_ * 512) + (size_t)(bqw + j) * 512 + halfh * 256;
            ((float4*)dst)[l] = z;
        }
    }

    cg::this_grid().sync();               // #1: cnt zeroed, WTf visible

    // ---- B fragment pointers + register triple-buffer (literal indices) -----
    const __bf16* bp[2][2];
    #pragma unroll
    for (int ni = 0; ni < 2; ++ni)
        #pragma unroll
        for (int kh = 0; kh < 2; ++kh)
            bp[ni][kh] = WTf + (size_t)(((w * 2 + ni) * 32 + kh) * 512 + l * 8);

    bf16x8 bre[3][2][2];
#define KT_OF(T) ((((ph4 + ((T) >> 2)) & 3) << 2) + ((T) & 3))
#define LOADB(B, T) {                                                         \
    const int kt_ = KT_OF(T);                                                 \
    _Pragma("unroll") for (int ni = 0; ni < 2; ++ni)                          \
        _Pragma("unroll") for (int kh = 0; kh < 2; ++kh)                      \
            bre[B][ni][kh] = *(const bf16x8*)(bp[ni][kh] + kt_ * 1024); }

    LOADB(0, 0)
    LOADB(1, 1)

    // ---- bucket atomics (cnt zeroed grid-wide at sync1) ---------------------
    if (gw < 512 && !halfh && ev >= sv) {
        int rr = bv * S_LEN + sv;
        int k = atomicAdd(&cnt[rr], 1); if (k < CAP) bucket[rr * CAP + k] = (qz << 2) | (seth << 1);
        rr = bv * S_LEN + ev;
        k = atomicAdd(&cnt[rr], 1);     if (k < CAP) bucket[rr * CAP + k] = (qz << 2) | (seth << 1) | 1;
    }

    cg::this_grid().sync();               // #2: buckets complete; Afl q0 visible

    // ---- quarter-pipelined compute chain (verified R9) ----------------------
    const int slotr = lm ^ (q << 1);
    const __bf16* abase = Afl + q * 128 + slotr * 8;   // + (mi*32+kt*2+kh)*512
    f32x4 acc[4][2] = {};

#define CSTEP(T) {                                                            \
    const int kt_ = KT_OF(T);                                                 \
    bf16x8 af[4][2];                                                          \
    _Pragma("unroll") for (int mi = 0; mi < 4; ++mi)                          \
        _Pragma("unroll") for (int kh = 0; kh < 2; ++kh)                      \
            af[mi][kh] = *(const bf16x8*)(abase + (mi * 32 + kt_ * 2 + kh) * 512); \
    _Pragma("unroll") for (int kh = 0; kh < 2; ++kh)                          \
        _Pragma("unroll") for (int mi = 0; mi < 4; ++mi)                      \
            _Pragma("unroll") for (int ni = 0; ni < 2; ++ni)                  \
                acc[mi][ni] = __builtin_amdgcn_mfma_f32_16x16x32_bf16(        \
                    af[mi][kh], bre[(T) % 3][ni][kh], acc[mi][ni], 0, 0, 0); }

    LOADB(2, 2) CSTEP(0) LOADB(0, 3) CSTEP(1) LOADB(1, 4) CSTEP(2) LOADB(2, 5) CSTEP(3)
    WRITEQ(q1, fB)               // fB landed during q0 compute
    LOADQ(q2, fA)
    __syncthreads();
    LOADB(0, 6) CSTEP(4) LOADB(1, 7) CSTEP(5) LOADB(2, 8) CSTEP(6) LOADB(0, 9) CSTEP(7)
    WRITEQ(q2, fA)
    LOADQ(q3, fB)
    __syncthreads();
    LOADB(1, 10) CSTEP(8) LOADB(2, 11) CSTEP(9) LOADB(0, 12) CSTEP(10) LOADB(1, 13) CSTEP(11)
    WRITEQ(q3, fB)
    __syncthreads();
    LOADB(2, 14) CSTEP(12) LOADB(0, 15) CSTEP(13) CSTEP(14) CSTEP(15)

#undef CSTEP
#undef LOADQ
#undef WRITEQ
#undef LOADB
#undef KT_OF

    // ---- fused epilogue (hs overlays Afl; barrier first) --------------------
    __syncthreads();                       // all waves done reading Afl
    float* hs = (float*)Afl;               // 64 x HS f32 = 66.6 KB < 128 KB

    if (tid < 64) { int c = cnt[m0 + tid]; s_cnt[tid] = c < CAP ? c : CAP; }

    // D layout: row = mi*16 + q*4 + r, col = w*32 + ni*16 + lm
    #pragma unroll
    for (int ni = 0; ni < 2; ++ni) {
        const int col = w * 32 + ni * 16 + lm;
        const float bv2 = bias[col];
        #pragma unroll
        for (int mi = 0; mi < 4; ++mi) {
            const int rbase = mi * 16 + q * 4;
            #pragma unroll
            for (int rr = 0; rr < 4; ++rr)
                hs[(rbase + rr) * HS + col] = acc[mi][ni][rr] + bv2;
        }
    }
    __syncthreads();
    if (tid == 0) {
        int a = 0;
        #pragma unroll 1
        for (int i = 0; i < 64; ++i) { s_off[i] = a; a += s_cnt[i]; }
        s_off[64] = a;
    }
    __syncthreads();
    if (tid < 64) {
        const int o = s_off[tid], c = s_cnt[tid];
        const int* bk = bucket + (size_t)(m0 + tid) * CAP;
        for (int k = 0; k < c; ++k)
            elist[o + k] = (tid << 15) | (bk[k] & 0x7fff);
    }
    __syncthreads();

    const int E  = s_off[64];
    const int gl = l;
    #pragma unroll 1
    for (int j = w; j < E; j += 8) {
        const int ent  = elist[j];
        const int rl   = ent >> 15;
        const int code = ent & 0x7fff;
        const int qq   = code >> 2;
        const int st   = (code >> 1) & 1;
        const int hf   = code & 1;
        const float4 v = *(const float4*)&hs[rl * HS + gl * 4];
        *(float4*)(out + (size_t)st * (NQ_ * 512) + (size_t)qq * 512 + hf * 256 + gl * 4) = v;
    }
}

// ---------------- launch ------------------------------------------------------
extern "C" void kernel_launch(void* const* d_in, const int* in_sizes, int n_in,
                              void* d_out, int out_size, void* d_ws, size_t ws_size,
                              hipStream_t stream) {
    const float* A    = (const float*)d_in[1];
    const int*   s1   = (const int*)  d_in[2];
    const int*   e1   = (const int*)  d_in[3];
    const int*   qb   = (const int*)  d_in[4];
    const int*   s2   = (const int*)  d_in[5];
    const int*   e2   = (const int*)  d_in[6];
    const float* W    = (const float*)d_in[7];
    const float* bias = (const float*)d_in[8];
    float*       out  = (float*)d_out;

    __bf16* WTf    = (__bf16*)d_ws;                                   // 512 KB
    int*    cnt    = (int*)((char*)d_ws + (1 << 20));                 // 64 KB
    int*    bucket = (int*)((char*)d_ws + (1 << 20) + (1 << 16));     // 2 MB

    void* args[] = { (void*)&A, (void*)&W, (void*)&bias,
                     (void*)&s1, (void*)&e1, (void*)&s2, (void*)&e2, (void*)&qb,
                     (void*)&cnt, (void*)&bucket, (void*)&WTf, (void*)&out };
    hipLaunchCooperativeKernel((void*)fused_kernel, dim3(M_TOT / 64), dim3(512),
                               args, 0, stream);
}

// Round 11
// 140.671 us; speedup vs baseline: 1.5331x; 1.5331x over previous
//
#include <hip/hip_runtime.h>
#include <hip/hip_bf16.h>
#include <stdint.h>

#define S_LEN 2048
#define D_DIM 1024
#define P_DIM 256
#define NQ_   8192
#define M_TOT 16384  // B*S
#define HS  260      // padded f32 row stride for H tile in LDS
#define WCAP 256     // per-wave elist capacity (mean ~8, 32x headroom)

typedef __attribute__((ext_vector_type(4))) float  f32x4;
typedef __attribute__((ext_vector_type(8))) __bf16 bf16x8;

// ============================================================================
// Fragment spec (harness-verified, lane l = q*16+lm):
//   A-frag(mi,kt,kh): lane l elem e = A[m0+mi*16+lm][kt*64+(kh*4+q)*8+e]
//     in LDS at (mi*32+kt*2+kh)*512 + qp*128 + (lm^(qp<<1))*8   (bank swizzle)
//   B-frag(c16,kt,kh) in WTf at (c16*32+kt*2+kh)*512 + l*8:
//     lane l elem e = W[kt*64+(kh*4+q)*8+e][c16*16+lm]
// ============================================================================

// ---------------- Kernel 0: W [1024][256] f32 -> WTf (fragment order) ---------
__global__ __launch_bounds__(1024) void wtf_kernel(const float* __restrict__ W,
                                                   __bf16* __restrict__ WTf) {
    __shared__ float tile[32][33];
    const int bx = blockIdx.x;            // k0 = bx*32 -> (kt = bx>>1, kh = bx&1)
    const int by = blockIdx.y;            // n0 = by*32 -> c16 in {2by, 2by+1}
    const int k0 = bx * 32, n0 = by * 32;
    const int tx = threadIdx.x, ty = threadIdx.y;
    tile[ty][tx] = W[(k0 + ty) * P_DIM + (n0 + tx)];   // coalesced
    __syncthreads();
    const int t = ty * 32 + tx;
    if (t < 128) {                        // 2 c16r * 4 q * 16 lm writers
        const int c16r = t >> 6, q = (t >> 4) & 3, lm = t & 15;
        bf16x8 v;
        #pragma unroll
        for (int e = 0; e < 8; ++e) v[e] = (__bf16)tile[q * 8 + e][c16r * 16 + lm];
        const int c16 = by * 2 + c16r;
        const int ts  = bx >> 1, kh = bx & 1;
        *(bf16x8*)(WTf + (size_t)((c16 * 32 + ts * 2 + kh) * 512 + (q * 16 + lm) * 8)) = v;
    }
}

// ---------------- Kernel 1: quarter-pipelined cvt+GEMM + local span scatter ---
// R9 skeleton (verified 132.5us) with the inverted-index kernel FOLDED IN:
// each wave scans queries [w*1024,+1024) x 2 sets against this block's 64
// rows, building a PRIVATE elist segment (LDS counter sEw[w]; no cross-wave
// sync), then zeroes invalid spans for its 8 owned (q,set) pairs. The scan's
// ~160 KB of L2-hot int loads overlap the in-flight A quarter loads. No
// cnt/bucket workspace, no separate index launch, no grid sync.
__global__ __launch_bounds__(512, 1) void gemm_kernel(const float*  __restrict__ A,
                                                      const __bf16* __restrict__ WTf,
                                                      const float*  __restrict__ bias,
                                                      const int*    __restrict__ s1,
                                                      const int*    __restrict__ e1,
                                                      const int*    __restrict__ s2,
                                                      const int*    __restrict__ e2,
                                                      const int*    __restrict__ qb,
                                                      float*        __restrict__ out) {
    __shared__ __align__(16) __bf16 Afl[65536];   // 128 KB A-panel fragments
    __shared__ int elist[8 * WCAP];               // 8 KB, per-wave segments
    __shared__ int sEw[8];

    const int tid = threadIdx.x;
    const int w   = tid >> 6;             // wave 0..7
    const int l   = tid & 63;
    const int lm  = l & 15;
    const int q   = l >> 4;

    const int bx  = blockIdx.x;
    const int m0  = bx * 64;
    const int ph4 = bx & 3;               // quarter stagger

    if (l == 0) sEw[w] = 0;               // wave-private; DS ops in-order per wave

    // ---- B fragment pointers + register triple-buffer (literal indices) -----
    const __bf16* bp[2][2];
    #pragma unroll
    for (int ni = 0; ni < 2; ++ni)
        #pragma unroll
        for (int kh = 0; kh < 2; ++kh)
            bp[ni][kh] = WTf + (size_t)(((w * 2 + ni) * 32 + kh) * 512 + l * 8);

    bf16x8 bre[3][2][2];
#define KT_OF(T) ((((ph4 + ((T) >> 2)) & 3) << 2) + ((T) & 3))
#define LOADB(B, T) {                                                         \
    const int kt_ = KT_OF(T);                                                 \
    _Pragma("unroll") for (int ni = 0; ni < 2; ++ni)                          \
        _Pragma("unroll") for (int kh = 0; kh < 2; ++kh)                      \
            bre[B][ni][kh] = *(const bf16x8*)(bp[ni][kh] + kt_ * 1024); }

    LOADB(0, 0)
    LOADB(1, 1)

    // ---- A staging geometry -------------------------------------------------
    const int r    = tid >> 3;
    const int la   = tid & 7;
    const int mi_s = r >> 4, lmr = r & 15;
    const float* asrc = A + (size_t)(m0 + r) * D_DIM;

    float4 fA[8], fB[8];
#define LOADQ(QQ, FR) {                                                       \
    _Pragma("unroll") for (int it = 0; it < 4; ++it) {                        \
        const int c = (QQ) * 32 + it * 8 + la;                                \
        FR[it * 2]     = *(const float4*)(asrc + c * 8);                      \
        FR[it * 2 + 1] = *(const float4*)(asrc + c * 8 + 4); } }
#define WRITEQ(QQ, FR) {                                                      \
    _Pragma("unroll") for (int it = 0; it < 4; ++it) {                        \
        const int c = (QQ) * 32 + it * 8 + la;                                \
        bf16x8 v;                                                             \
        v[0] = (__bf16)FR[it*2].x;   v[1] = (__bf16)FR[it*2].y;               \
        v[2] = (__bf16)FR[it*2].z;   v[3] = (__bf16)FR[it*2].w;               \
        v[4] = (__bf16)FR[it*2+1].x; v[5] = (__bf16)FR[it*2+1].y;             \
        v[6] = (__bf16)FR[it*2+1].z; v[7] = (__bf16)FR[it*2+1].w;             \
        const int kt = c >> 3, kh = (c >> 2) & 1, qp = c & 3;                 \
        const int slot = lmr ^ (qp << 1);                                     \
        *(bf16x8*)(&Afl[(mi_s * 32 + kt * 2 + kh) * 512 + qp * 128 + slot * 8]) = v; } }

    const int q0 = ph4, q1 = (ph4 + 1) & 3, q2 = (ph4 + 2) & 3, q3 = (ph4 + 3) & 3;

    LOADQ(q0, fA)                         // oldest in queue: WRITEQ's counted
    LOADQ(q1, fB)                         // vmcnt wait is unaffected by scan

    // ---- span scan: build this block's consumer list (overlaps A latency) ---
    #pragma unroll
    for (int set = 0; set < 2; ++set) {
        const int* sA = set ? s2 : s1;
        const int* eA = set ? e2 : e1;
        #pragma unroll 4
        for (int i = 0; i < 16; ++i) {
            const int qq = w * 1024 + i * 64 + l;
            const int s  = sA[qq];
            const int e  = eA[qq];
            if (e >= s) {
                const int b  = qb[qq];
                const int rs = b * S_LEN + s - m0;
                const int re = b * S_LEN + e - m0;
                if ((unsigned)rs < 64u) {
                    const int k = atomicAdd(&sEw[w], 1);
                    if (k < WCAP) elist[w * WCAP + k] = (rs << 15) | (qq << 2) | (set << 1);
                }
                if ((unsigned)re < 64u) {
                    const int k = atomicAdd(&sEw[w], 1);
                    if (k < WCAP) elist[w * WCAP + k] = (re << 15) | (qq << 2) | (set << 1) | 1;
                }
            }
        }
    }
    // ---- invalid-span zeroing: wave w owns pairs [w*8, w*8+8) of this
    // block's 32 queries x 2 sets (exactly one writer per span grid-wide).
    {
        const float4 z = make_float4(0.f, 0.f, 0.f, 0.f);
        #pragma unroll 1
        for (int p = 0; p < 8; ++p) {
            const int pair = w * 8 + p;
            const int qq   = bx * 32 + (pair >> 1);
            const int set  = pair & 1;
            const int s = set ? s2[qq] : s1[qq];
            const int e = set ? e2[qq] : e1[qq];
            if (e < s) {
                float* dst = out + (size_t)set * (NQ_ * 512) + (size_t)qq * 512;
                ((float4*)dst)[l]      = z;
                ((float4*)dst)[l + 64] = z;
            }
        }
    }

    WRITEQ(q0, fA)               // counted vmcnt: waits fA only
    __syncthreads();             // quarter q0 visible

    const int slotr = lm ^ (q << 1);
    const __bf16* abase = Afl + q * 128 + slotr * 8;   // + (mi*32+kt*2+kh)*512
    f32x4 acc[4][2] = {};

#define CSTEP(T) {                                                            \
    const int kt_ = KT_OF(T);                                                 \
    bf16x8 af[4][2];                                                          \
    _Pragma("unroll") for (int mi = 0; mi < 4; ++mi)                          \
        _Pragma("unroll") for (int kh = 0; kh < 2; ++kh)                      \
            af[mi][kh] = *(const bf16x8*)(abase + (mi * 32 + kt_ * 2 + kh) * 512); \
    _Pragma("unroll") for (int kh = 0; kh < 2; ++kh)                          \
        _Pragma("unroll") for (int mi = 0; mi < 4; ++mi)                      \
            _Pragma("unroll") for (int ni = 0; ni < 2; ++ni)                  \
                acc[mi][ni] = __builtin_amdgcn_mfma_f32_16x16x32_bf16(        \
                    af[mi][kh], bre[(T) % 3][ni][kh], acc[mi][ni], 0, 0, 0); }

    LOADB(2, 2) CSTEP(0) LOADB(0, 3) CSTEP(1) LOADB(1, 4) CSTEP(2) LOADB(2, 5) CSTEP(3)
    WRITEQ(q1, fB)               // fB landed during q0 compute
    LOADQ(q2, fA)
    __syncthreads();
    LOADB(0, 6) CSTEP(4) LOADB(1, 7) CSTEP(5) LOADB(2, 8) CSTEP(6) LOADB(0, 9) CSTEP(7)
    WRITEQ(q2, fA)
    LOADQ(q3, fB)
    __syncthreads();
    LOADB(1, 10) CSTEP(8) LOADB(2, 11) CSTEP(9) LOADB(0, 12) CSTEP(10) LOADB(1, 13) CSTEP(11)
    WRITEQ(q3, fB)
    __syncthreads();
    LOADB(2, 14) CSTEP(12) LOADB(0, 15) CSTEP(13) CSTEP(14) CSTEP(15)

#undef CSTEP
#undef LOADQ
#undef WRITEQ
#undef LOADB
#undef KT_OF

    // ---- fused epilogue (hs overlays Afl; barrier first) --------------------
    __syncthreads();                       // all waves done reading Afl
    float* hs = (float*)Afl;               // 64 x HS f32 = 66.6 KB < 128 KB

    // D layout: row = mi*16 + q*4 + r, col = w*32 + ni*16 + lm
    #pragma unroll
    for (int ni = 0; ni < 2; ++ni) {
        const int col = w * 32 + ni * 16 + lm;
        const float bv = bias[col];
        #pragma unroll
        for (int mi = 0; mi < 4; ++mi) {
            const int rbase = mi * 16 + q * 4;
            #pragma unroll
            for (int rr = 0; rr < 4; ++rr)
                hs[(rbase + rr) * HS + col] = acc[mi][ni][rr] + bv;
        }
    }
    __syncthreads();

    // ---- scatter: wave w drains its own elist segment -----------------------
    const int E = sEw[w] < WCAP ? sEw[w] : WCAP;
    #pragma unroll 1
    for (int j = 0; j < E; ++j) {
        const int ent  = elist[w * WCAP + j];
        const int rl   = ent >> 15;
        const int code = ent & 0x7fff;
        const int qq   = code >> 2;
        const int st   = (code >> 1) & 1;
        const int hf   = code & 1;
        const float4 v = *(const float4*)&hs[rl * HS + l * 4];
        *(float4*)(out + (size_t)st * (NQ_ * 512) + (size_t)qq * 512 + hf * 256 + l * 4) = v;
    }
}

// ---------------- launch ------------------------------------------------------
extern "C" void kernel_launch(void* const* d_in, const int* in_sizes, int n_in,
                              void* d_out, int out_size, void* d_ws, size_t ws_size,
                              hipStream_t stream) {
    const float* A    = (const float*)d_in[1];
    const int*   s1   = (const int*)  d_in[2];
    const int*   e1   = (const int*)  d_in[3];
    const int*   qb   = (const int*)  d_in[4];
    const int*   s2   = (const int*)  d_in[5];
    const int*   e2   = (const int*)  d_in[6];
    const float* W    = (const float*)d_in[7];
    const float* bias = (const float*)d_in[8];
    float*       out  = (float*)d_out;

    __bf16* WTf = (__bf16*)d_ws;                                      // 512 KB

    wtf_kernel <<<dim3(32, 8), dim3(32, 32), 0, stream>>>(W, WTf);
    gemm_kernel<<<dim3(M_TOT / 64), dim3(512), 0, stream>>>(A, WTf, bias,
                                                            s1, e1, s2, e2, qb, out);
}

// Round 12
// 135.259 us; speedup vs baseline: 1.5945x; 1.0400x over previous
//
#include <hip/hip_runtime.h>
#include <hip/hip_bf16.h>
#include <stdint.h>

#define S_LEN 2048
#define D_DIM 1024
#define P_DIM 256
#define NQ_   8192
#define M_TOT 16384  // B*S
#define CAP 32       // max span-endpoints per H row
#define HS  260      // padded f32 row stride for H tile in LDS

typedef __attribute__((ext_vector_type(4))) float  f32x4;
typedef __attribute__((ext_vector_type(8))) __bf16 bf16x8;

// ============================================================================
// Fragment spec (harness-verified, lane l = q*16+lm):
//   A-frag(mi,kt,kh): lane l elem e = A[m0+mi*16+lm][kt*64+(kh*4+q)*8+e]
//     in LDS at (mi*32+kt*2+kh)*512 + qp*128 + (lm^(qp<<1))*8   (bank swizzle)
//   B-frag(c16,kt,kh) in WTf at (c16*32+kt*2+kh)*512 + l*8:
//     lane l elem e = W[kt*64+(kh*4+q)*8+e][c16*16+lm]
// ============================================================================

// ---------------- Kernel 0: merged prep (wtf transform + span index/zero) -----
// Blocks 0..255: W 32x32 tile -> WTf fragment store (verified wtf algebra,
//   flattened 1024-thr indexing). Blocks 256..287: 4 index-units each of the
//   verified index_zero body (wave = one (unit,set,half) x 64 q -> ballot
//   semantics identical). cnt is zeroed by hipMemsetAsync BEFORE this launch,
//   so both halves are order-independent.
__global__ __launch_bounds__(1024) void prep_kernel(const float* __restrict__ W,
                                                    __bf16* __restrict__ WTf,
                                                    const int* __restrict__ s1,
                                                    const int* __restrict__ e1,
                                                    const int* __restrict__ s2,
                                                    const int* __restrict__ e2,
                                                    const int* __restrict__ qb,
                                                    int* __restrict__ cnt,
                                                    int* __restrict__ bucket,
                                                    float* __restrict__ out) {
    __shared__ float tile[32][33];
    const int bid = blockIdx.x;
    const int tid = threadIdx.x;

    if (bid < 256) {
        // ---- wtf path: bx = k-tile 0..31, by = n-tile 0..7 ----
        const int bx = bid & 31, by = bid >> 5;
        const int k0 = bx * 32, n0 = by * 32;
        const int tx = tid & 31, ty = tid >> 5;           // ty 0..31
        tile[ty][tx] = W[(k0 + ty) * P_DIM + (n0 + tx)];  // coalesced
        __syncthreads();
        if (tid < 128) {                      // 2 c16r * 4 q * 16 lm writers
            const int c16r = tid >> 6, q = (tid >> 4) & 3, lm = tid & 15;
            bf16x8 v;
            #pragma unroll
            for (int e = 0; e < 8; ++e) v[e] = (__bf16)tile[q * 8 + e][c16r * 16 + lm];
            const int c16 = by * 2 + c16r;
            const int ts  = bx >> 1, kh = bx & 1;
            *(bf16x8*)(WTf + (size_t)((c16 * 32 + ts * 2 + kh) * 512 + (q * 16 + lm) * 8)) = v;
        }
    } else {
        // ---- index path: unit u 0..127, wave-aligned (set,half) ----
        const int u    = (bid - 256) * 4 + (tid >> 8);
        const int t    = tid & 255;
        const int lane = t & 63;
        const int q    = u * 64 + lane;
        const int set  = t >> 7;
        const int half = (t >> 6) & 1;
        const int b    = qb[q];
        const int s = set ? s2[q] : s1[q];
        const int e = set ? e2[q] : e1[q];
        if (!half && e >= s) {
            int r = b * S_LEN + s;
            int k = atomicAdd(&cnt[r], 1); if (k < CAP) bucket[r * CAP + k] = (q << 2) | (set << 1);
            r = b * S_LEN + e;
            k = atomicAdd(&cnt[r], 1);     if (k < CAP) bucket[r * CAP + k] = (q << 2) | (set << 1) | 1;
        }
        unsigned long long mask = __ballot(e < s);
        const int bqw = u * 64;
        const float4 z = make_float4(0.f, 0.f, 0.f, 0.f);
        while (mask) {
            const int j = __ffsll(mask) - 1;
            mask &= mask - 1;
            float* dst = out + (size_t)set * (NQ_ * 512) + (size_t)(bqw + j) * 512 + half * 256;
            ((float4*)dst)[lane] = z;
        }
    }
}

// ---------------- Kernel 1: quarter-pipelined cvt+GEMM + span scatter ---------
// VERBATIM R9 (verified 132.5us): BM=64, 256 blocks x 512 thr, A-panel in 4
// K-quarters software-pipelined (issue-early/write-late), per-block quarter
// stagger ph4, B register triple-buffer with literal indices, fused span
// scatter epilogue from the LDS H-tile.
__global__ __launch_bounds__(512, 1) void gemm_kernel(const float*  __restrict__ A,
                                                      const __bf16* __restrict__ WTf,
                                                      const float*  __restrict__ bias,
                                                      const int*    __restrict__ cnt,
                                                      const int*    __restrict__ bucket,
                                                      float*        __restrict__ out) {
    __shared__ __align__(16) __bf16 Afl[65536];   // 128 KB A-panel fragments
    __shared__ int s_cnt[64];
    __shared__ int s_off[65];
    __shared__ int elist[64 * CAP];

    const int tid = threadIdx.x;
    const int w   = tid >> 6;             // wave 0..7
    const int l   = tid & 63;
    const int lm  = l & 15;
    const int q   = l >> 4;

    const int m0  = blockIdx.x * 64;
    const int ph4 = blockIdx.x & 3;       // quarter stagger

    // ---- B fragment pointers + register triple-buffer (literal indices) -----
    const __bf16* bp[2][2];
    #pragma unroll
    for (int ni = 0; ni < 2; ++ni)
        #pragma unroll
        for (int kh = 0; kh < 2; ++kh)
            bp[ni][kh] = WTf + (size_t)(((w * 2 + ni) * 32 + kh) * 512 + l * 8);

    bf16x8 bre[3][2][2];
    // compute-step T (0..15) -> kt = ((ph4 + T/4)&3)*4 + (T&3)
#define KT_OF(T) ((((ph4 + ((T) >> 2)) & 3) << 2) + ((T) & 3))
#define LOADB(B, T) {                                                         \
    const int kt_ = KT_OF(T);                                                 \
    _Pragma("unroll") for (int ni = 0; ni < 2; ++ni)                          \
        _Pragma("unroll") for (int kh = 0; kh < 2; ++kh)                      \
            bre[B][ni][kh] = *(const bf16x8*)(bp[ni][kh] + kt_ * 1024); }

    LOADB(0, 0)
    LOADB(1, 1)

    // ---- A staging: thread t -> row tid>>3, chunk-lane la = tid&7.
    // Quarter qq covers chunks c = qq*32 + it*8 + la, it = 0..3.
    const int r    = tid >> 3;
    const int la   = tid & 7;
    const int mi_s = r >> 4, lmr = r & 15;
    const float* asrc = A + (size_t)(m0 + r) * D_DIM;

    float4 fA[8], fB[8];
#define LOADQ(QQ, FR) {                                                       \
    _Pragma("unroll") for (int it = 0; it < 4; ++it) {                        \
        const int c = (QQ) * 32 + it * 8 + la;                                \
        FR[it * 2]     = *(const float4*)(asrc + c * 8);                      \
        FR[it * 2 + 1] = *(const float4*)(asrc + c * 8 + 4); } }
#define WRITEQ(QQ, FR) {                                                      \
    _Pragma("unroll") for (int it = 0; it < 4; ++it) {                        \
        const int c = (QQ) * 32 + it * 8 + la;                                \
        bf16x8 v;                                                             \
        v[0] = (__bf16)FR[it*2].x;   v[1] = (__bf16)FR[it*2].y;               \
        v[2] = (__bf16)FR[it*2].z;   v[3] = (__bf16)FR[it*2].w;               \
        v[4] = (__bf16)FR[it*2+1].x; v[5] = (__bf16)FR[it*2+1].y;             \
        v[6] = (__bf16)FR[it*2+1].z; v[7] = (__bf16)FR[it*2+1].w;             \
        const int kt = c >> 3, kh = (c >> 2) & 1, qp = c & 3;                 \
        const int slot = lmr ^ (qp << 1);                                     \
        *(bf16x8*)(&Afl[(mi_s * 32 + kt * 2 + kh) * 512 + qp * 128 + slot * 8]) = v; } }

    const int slotr = lm ^ (q << 1);
    const __bf16* abase = Afl + q * 128 + slotr * 8;   // + (mi*32+kt*2+kh)*512
    f32x4 acc[4][2] = {};

#define CSTEP(T) {                                                            \
    const int kt_ = KT_OF(T);                                                 \
    bf16x8 af[4][2];                                                          \
    _Pragma("unroll") for (int mi = 0; mi < 4; ++mi)                          \
        _Pragma("unroll") for (int kh = 0; kh < 2; ++kh)                      \
            af[mi][kh] = *(const bf16x8*)(abase + (mi * 32 + kt_ * 2 + kh) * 512); \
    _Pragma("unroll") for (int kh = 0; kh < 2; ++kh)                          \
        _Pragma("unroll") for (int mi = 0; mi < 4; ++mi)                      \
            _Pragma("unroll") for (int ni = 0; ni < 2; ++ni)                  \
                acc[mi][ni] = __builtin_amdgcn_mfma_f32_16x16x32_bf16(        \
                    af[mi][kh], bre[(T) % 3][ni][kh], acc[mi][ni], 0, 0, 0); }

    const int q0 = ph4, q1 = (ph4 + 1) & 3, q2 = (ph4 + 2) & 3, q3 = (ph4 + 3) & 3;

    LOADQ(q0, fA)
    LOADQ(q1, fB)                // in flight under q0's write + compute
    WRITEQ(q0, fA)               // counted vmcnt: waits fA only
    __syncthreads();             // quarter q0 visible
    LOADB(2, 2) CSTEP(0) LOADB(0, 3) CSTEP(1) LOADB(1, 4) CSTEP(2) LOADB(2, 5) CSTEP(3)
    WRITEQ(q1, fB)               // fB landed during q0 compute
    LOADQ(q2, fA)
    __syncthreads();
    LOADB(0, 6) CSTEP(4) LOADB(1, 7) CSTEP(5) LOADB(2, 8) CSTEP(6) LOADB(0, 9) CSTEP(7)
    WRITEQ(q2, fA)
    LOADQ(q3, fB)
    __syncthreads();
    LOADB(1, 10) CSTEP(8) LOADB(2, 11) CSTEP(9) LOADB(0, 12) CSTEP(10) LOADB(1, 13) CSTEP(11)
    WRITEQ(q3, fB)
    __syncthreads();
    LOADB(2, 14) CSTEP(12) LOADB(0, 15) CSTEP(13) CSTEP(14) CSTEP(15)

#undef CSTEP
#undef LOADQ
#undef WRITEQ
#undef LOADB
#undef KT_OF

    // ---- fused epilogue (hs overlays Afl; barrier first) --------------------
    __syncthreads();                       // all waves done reading Afl
    float* hs = (float*)Afl;               // 64 x HS f32 = 66.6 KB < 128 KB

    if (tid < 64) { int c = cnt[m0 + tid]; s_cnt[tid] = c < CAP ? c : CAP; }

    // D layout: row = mi*16 + q*4 + r, col = w*32 + ni*16 + lm
    #pragma unroll
    for (int ni = 0; ni < 2; ++ni) {
        const int col = w * 32 + ni * 16 + lm;
        const float bv = bias[col];
        #pragma unroll
        for (int mi = 0; mi < 4; ++mi) {
            const int rbase = mi * 16 + q * 4;
            #pragma unroll
            for (int rr = 0; rr < 4; ++rr)
                hs[(rbase + rr) * HS + col] = acc[mi][ni][rr] + bv;
        }
    }
    __syncthreads();
    if (tid == 0) {
        int a = 0;
        #pragma unroll 1
        for (int i = 0; i < 64; ++i) { s_off[i] = a; a += s_cnt[i]; }
        s_off[64] = a;
    }
    __syncthreads();
    if (tid < 64) {
        const int o = s_off[tid], c = s_cnt[tid];
        const int* bk = bucket + (size_t)(m0 + tid) * CAP;
        for (int k = 0; k < c; ++k)
            elist[o + k] = (tid << 15) | (bk[k] & 0x7fff);
    }
    __syncthreads();

    const int E   = s_off[64];
    const int grp = tid >> 6;
    const int gl  = tid & 63;
    #pragma unroll 1
    for (int j = grp; j < E; j += 8) {
        const int ent  = elist[j];
        const int rl   = ent >> 15;
        const int code = ent & 0x7fff;
        const int qq   = code >> 2;
        const int st   = (code >> 1) & 1;
        const int hf   = code & 1;
        const float4 v = *(const float4*)&hs[rl * HS + gl * 4];
        *(float4*)(out + (size_t)st * (NQ_ * 512) + (size_t)qq * 512 + hf * 256 + gl * 4) = v;
    }
}

// ---------------- launch ------------------------------------------------------
extern "C" void kernel_launch(void* const* d_in, const int* in_sizes, int n_in,
                              void* d_out, int out_size, void* d_ws, size_t ws_size,
                              hipStream_t stream) {
    const float* A    = (const float*)d_in[1];
    const int*   s1   = (const int*)  d_in[2];
    const int*   e1   = (const int*)  d_in[3];
    const int*   qb   = (const int*)  d_in[4];
    const int*   s2   = (const int*)  d_in[5];
    const int*   e2   = (const int*)  d_in[6];
    const float* W    = (const float*)d_in[7];
    const float* bias = (const float*)d_in[8];
    float*       out  = (float*)d_out;

    __bf16* WTf    = (__bf16*)d_ws;                                   // 512 KB
    int*    cnt    = (int*)((char*)d_ws + (1 << 20));                 // 64 KB
    int*    bucket = (int*)((char*)d_ws + (1 << 20) + (1 << 16));     // 2 MB

    hipMemsetAsync((void*)cnt, 0, M_TOT * sizeof(int), stream);
    prep_kernel<<<dim3(288), dim3(1024), 0, stream>>>(W, WTf, s1, e1, s2, e2, qb,
                                                      cnt, bucket, out);
    gemm_kernel<<<dim3(M_TOT / 64), dim3(512), 0, stream>>>(A, WTf, bias,
                                                            cnt, bucket, out);
}